// Round 12
// baseline (87.274 us; speedup 1.0000x reference)
//
#include <hip/hip_runtime.h>
#include <stdint.h>

// LearnedTripleConnect: B=8,N=8192,S=8,D=64. out[b,n] = mean_s( gelu([xi|xj|xk]W1+b1) ) W2 + b2
// Round 12: round-11 with the nontemporal builtin type fix (ext_vector f32x4 instead of
// HIP float4). Split path, L2-managed: PA/x/out marked nt, PG normal (XCD-L2-resident).

typedef short  short8 __attribute__((ext_vector_type(8)));
typedef float  f32x2  __attribute__((ext_vector_type(2)));
typedef float  f32x4  __attribute__((ext_vector_type(4)));
typedef float  f32x16 __attribute__((ext_vector_type(16)));
typedef _Float16 h16x2 __attribute__((ext_vector_type(2)));
typedef _Float16 h16x4 __attribute__((ext_vector_type(4)));

__device__ __forceinline__ unsigned cvtpk(float lo, float hi){
  unsigned r;
  asm("v_cvt_pk_bf16_f32 %0, %1, %2" : "=v"(r) : "v"(lo), "v"(hi));
  return r;
}
__device__ __forceinline__ f32x2 gelu2(f32x2 x){
  f32x2 x2 = x * x;
  f32x2 t  = x2 * (-0.1029437f) + (-2.3022083f);
  f32x2 xt = x * t;
  f32x2 r;
  r[0] = __builtin_amdgcn_rcpf(1.0f + __builtin_amdgcn_exp2f(xt[0]));
  r[1] = __builtin_amdgcn_rcpf(1.0f + __builtin_amdgcn_exp2f(xt[1]));
  return x * r;
}

// ---------------- P-GEMM: PA/PG = x @ W', C^T orientation, in-kernel frag build ----------------
__global__ __launch_bounds__(256, 4) void pgemm(
    const float* __restrict__ x, const float* __restrict__ W1,
    _Float16* __restrict__ PA, _Float16* __restrict__ PG)
{
  const int tid = threadIdx.x;
  const int w = tid >> 6, lane = tid & 63;
  const int l31 = lane & 31, hi = lane >> 5;
  const int bid = blockIdx.x;
  const int n0 = (bid & 7) * 8192 + (bid >> 3) * 32;    // batch-affine XCD swizzle

  // W1 fragments for this wave's 3 cb, built from f32 W1 (hot in L1/L2)
  short8 wfr[3][4];
  #pragma unroll
  for (int ci = 0; ci < 3; ci++){
    const int cb = w * 3 + ci;
    const int col = (cb & 3) * 32 + l31;
    #pragma unroll
    for (int t = 0; t < 4; t++){
      const int rb = (cb >> 2) * 64 + t * 16 + 8 * hi;
      const float* wp = W1 + (long)rb * 128 + col;
      union { unsigned u[4]; short8 s; } cv;
      #pragma unroll
      for (int p = 0; p < 4; p++)
        cv.u[p] = cvtpk(wp[(2*p) * 128], wp[(2*p + 1) * 128]);
      wfr[ci][t] = cv.s;
    }
  }

  // x-frags (B-operand): B[k = 8hi+j][col = n = l31], nt loads
  short8 xf[4];
  #pragma unroll
  for (int t = 0; t < 4; t++){
    const f32x4* xr = (const f32x4*)(x + (long)(n0 + l31) * 64 + t * 16 + 8 * hi);
    f32x4 a = __builtin_nontemporal_load(xr);
    f32x4 b = __builtin_nontemporal_load(xr + 1);
    union { unsigned u[4]; short8 s; } cv;
    cv.u[0] = cvtpk(a[0], a[1]); cv.u[1] = cvtpk(a[2], a[3]);
    cv.u[2] = cvtpk(b[0], b[1]); cv.u[3] = cvtpk(b[2], b[3]);
    xf[t] = cv.s;
  }

  #pragma unroll
  for (int ci = 0; ci < 3; ci++){
    const int cb = w * 3 + ci;                          // 0..11 = slice*4 + hblock
    f32x16 acc;
    #pragma unroll
    for (int r = 0; r < 16; r++) acc[r] = 0.f;
    #pragma unroll
    for (int t = 0; t < 4; t++)
      acc = __builtin_amdgcn_mfma_f32_32x32x16_bf16(wfr[ci][t], xf[t], acc, 0, 0, 0);

    // C^T[h][n]: col l31 = n, reg 4g+i -> h = hblock*32 + 8g + 4hi + i
    #pragma unroll
    for (int g = 0; g < 4; g++){
      h16x4 pk;
      pk[0] = (_Float16)acc[4*g+0]; pk[1] = (_Float16)acc[4*g+1];
      pk[2] = (_Float16)acc[4*g+2]; pk[3] = (_Float16)acc[4*g+3];
      if (cb < 4){
        h16x4* dst = (h16x4*)(PA + (long)(n0 + l31) * 128 + cb * 32 + 8 * g + 4 * hi);
        __builtin_nontemporal_store(pk, dst);           // PA: streamed, keep out of L2
      } else {
        h16x4* dst = (h16x4*)(PG + (long)(n0 + l31) * 256 + (cb - 4) * 32 + 8 * g + 4 * hi);
        *dst = pk;                                      // PG: normal -> warm the XCD L2
      }
    }
  }
}

// ---------------- main: gather PG + gelu + mean_s + GEMM2 ----------------
__global__ __launch_bounds__(256, 4) void ltc_main(
    const _Float16* __restrict__ PA, const _Float16* __restrict__ PG,
    const float* __restrict__ W2,
    const int* __restrict__ jidx,   const int* __restrict__ kidx,
    const float* __restrict__ b1,   const float* __restrict__ b2,
    float* __restrict__ out)
{
  __shared__ short HB[2][16 * 136];   // hbar ping-pong: 16 n-rows x 128 h (bf16), stride 136

  const int tid  = threadIdx.x;
  const int w    = tid >> 6, lane = tid & 63;
  const int l15  = lane & 15, q4 = lane >> 4;

  // W2 fragments built from f32 W2 (hot)
  short8 w2v[4];
  #pragma unroll
  for (int q2 = 0; q2 < 4; q2++){
    const float* wp = W2 + (long)(q2 * 32 + 8 * q4) * 64 + w * 16 + l15;
    union { unsigned u[4]; short8 s; } cv;
    #pragma unroll
    for (int p = 0; p < 4; p++)
      cv.u[p] = cvtpk(wp[(2*p) * 64], wp[(2*p + 1) * 64]);
    w2v[q2] = cv.s;
  }
  const float b2v = b2[w * 16 + l15];
  const float2 b1p = *(const float2*)(b1 + lane * 2);   // b1 for h = 2*lane, 2*lane+1

  const int bid   = blockIdx.x;
  const int batch = bid & 7;
  const int gbase = batch * 8192 + (bid >> 3) * 64;     // first global n of this block
  const unsigned bb = (unsigned)(batch << 13);

  auto gemm2_store = [&](int hb, int ttp){
    f32x4 acc2 = {0.f, 0.f, 0.f, 0.f};
    #pragma unroll
    for (int q2 = 0; q2 < 4; q2++){
      short8 hbf = *(const short8*)((const char*)&HB[hb][0] + l15 * 272 + q2 * 64 + q4 * 16);
      acc2 = __builtin_amdgcn_mfma_f32_16x16x32_bf16(hbf, w2v[q2], acc2, 0, 0, 0);
    }
    long Gn = (long)(gbase + ttp * 16);
    #pragma unroll
    for (int r = 0; r < 4; r++)
      __builtin_nontemporal_store(acc2[r] + b2v,
          &out[(Gn + 4 * q4 + r) * 64 + w * 16 + l15]);
  };

  for (int tt = 0; tt < 4; ++tt){
    asm volatile("s_waitcnt lgkmcnt(0)\n\ts_barrier" ::: "memory");  // HB[(tt-1)&1] published
    if (tt > 0) gemm2_store((tt ^ 1) & 1, tt - 1);

    #pragma unroll
    for (int u = 0; u < 4; u++){
      const int nl = w * 4 + u;                 // n-row in tile (0..15)
      const int gn = gbase + tt * 16 + nl;
      const int4 j0 = *(const int4*)(jidx + (long)gn * 8);
      const int4 j1 = *(const int4*)(jidx + (long)gn * 8 + 4);
      const int4 k0 = *(const int4*)(kidx + (long)gn * 8);
      const int4 k1 = *(const int4*)(kidx + (long)gn * 8 + 4);
      const int jv[8] = {j0.x, j0.y, j0.z, j0.w, j1.x, j1.y, j1.z, j1.w};
      const int kv[8] = {k0.x, k0.y, k0.z, k0.w, k1.x, k1.y, k1.z, k1.w};

      union { unsigned u32; h16x2 h; } avu;
      avu.u32 = __builtin_nontemporal_load((const unsigned*)(PA + (long)gn * 128) + lane);
      f32x2 af; af[0] = (float)avu.h[0] + b1p.x; af[1] = (float)avu.h[1] + b1p.y;

      f32x2 hs = {0.f, 0.f};
      #pragma unroll
      for (int s = 0; s < 8; s++){
        h16x2 v1 = *(const h16x2*)(PG + (long)(bb + (unsigned)jv[s]) * 256 + lane * 2);
        h16x2 v2 = *(const h16x2*)(PG + (long)(bb + (unsigned)kv[s]) * 256 + 128 + lane * 2);
        h16x2 vs = v1 + v2;                     // v_pk_add_f16
        f32x2 z;
        z[0] = af[0] + (float)vs[0];
        z[1] = af[1] + (float)vs[1];
        hs += gelu2(z);
      }
      hs *= 0.125f;
      *(unsigned*)&HB[tt & 1][nl * 136 + lane * 2] = cvtpk(hs[0], hs[1]);
    }
  }

  asm volatile("s_waitcnt lgkmcnt(0)\n\ts_barrier" ::: "memory");
  gemm2_store(1, 3);
}

// ---------------- fallback (ws too small): correct, slow ----------------
__global__ void ltc_naive(const float* __restrict__ x, const int* __restrict__ jidx,
                          const int* __restrict__ kidx, const float* __restrict__ W1,
                          const float* __restrict__ b1, const float* __restrict__ W2,
                          const float* __restrict__ b2, float* __restrict__ out)
{
  int gidx = blockIdx.x;            // b*8192+n
  int b = gidx >> 13;
  __shared__ float trip[8][192];
  __shared__ float hb[128];
  int t = threadIdx.x;              // 128
  for (int i = t; i < 8 * 192; i += 128){
    int s = i / 192, c = i - s * 192;
    int v = c >> 6, cc = c & 63;
    int src;
    if (v == 0)      src = gidx & 8191;
    else if (v == 1) src = jidx[gidx * 8 + s];
    else             src = kidx[gidx * 8 + s];
    trip[s][c] = x[((long)(b << 13) + src) * 64 + cc];
  }
  __syncthreads();
  float z[8];
  #pragma unroll
  for (int s = 0; s < 8; s++) z[s] = b1[t];
  for (int k = 0; k < 192; k++){
    float wv = W1[k * 128 + t];
    #pragma unroll
    for (int s = 0; s < 8; s++) z[s] = fmaf(trip[s][k], wv, z[s]);
  }
  float acc = 0.f;
  #pragma unroll
  for (int s = 0; s < 8; s++){
    f32x2 zz; zz[0] = z[s]; zz[1] = z[s];
    acc += gelu2(zz)[0];
  }
  hb[t] = acc * 0.125f;
  __syncthreads();
  if (t < 64){
    float o = b2[t];
    for (int h = 0; h < 128; h++) o = fmaf(hb[h], W2[h * 64 + t], o);
    out[(long)gidx * 64 + t] = o;
  }
}

extern "C" void kernel_launch(void* const* d_in, const int* in_sizes, int n_in,
                              void* d_out, int out_size, void* d_ws, size_t ws_size,
                              hipStream_t stream) {
  const float* x   = (const float*)d_in[0];
  const int*   jix = (const int*)  d_in[1];
  const int*   kix = (const int*)  d_in[2];
  const float* W1  = (const float*)d_in[3];
  const float* b1  = (const float*)d_in[4];
  const float* W2  = (const float*)d_in[5];
  const float* b2  = (const float*)d_in[6];
  float* out = (float*)d_out;

  const size_t pa_elems = (size_t)65536 * 128;          // fp16
  const size_t pg_elems = (size_t)65536 * 256;          // fp16
  const size_t need = (pa_elems + pg_elems) * 2;

  if (ws_size >= need){
    _Float16* PA = (_Float16*)d_ws;
    _Float16* PG = PA + pa_elems;
    pgemm<<<2048, 256, 0, stream>>>(x, W1, PA, PG);
    ltc_main<<<1024, 256, 0, stream>>>(PA, PG, W2, jix, kix, b1, b2, out);
  } else {
    ltc_naive<<<8 * 8192, 128, 0, stream>>>(x, jix, kix, W1, b1, W2, b2, out);
  }
}

// Round 13
// 59.349 us; speedup vs baseline: 1.4705x; 1.4705x over previous
//
#include <hip/hip_runtime.h>
#include <stdint.h>

// LearnedTripleConnect: B=8,N=8192,S=8,D=64. out[b,n] = mean_s( gelu([xi|xj|xk]W1+b1) ) W2 + b2
// Round 13: r7 structure (4-wave blocks, 32-tok tiles, chunk-major LDS, 1 barrier/tile,
// deferred GEMM2) at 8-waves/SIMD VGPR budget -> 7 blocks/CU = 28 waves/CU (was 16).

#define NT   8            // 32-token tiles per block
#define NBLK 2048         // 2048*8*32 = 524288 tokens

typedef short  short8 __attribute__((ext_vector_type(8)));
typedef float  f32x4  __attribute__((ext_vector_type(4)));
typedef float  f32x16 __attribute__((ext_vector_type(16)));

__device__ __forceinline__ unsigned short f2bf(float f){
  union { float f; unsigned u; } a; a.f = f;
  unsigned u = a.u;
  u += 0x7fffu + ((u >> 16) & 1u);   // RNE
  return (unsigned short)(u >> 16);
}
__device__ __forceinline__ float fast_gelu(float x){
  // x * sigmoid(1.5957691*(x + 0.044715 x^3)) via exp2; |err vs exact gelu| ~3e-4
  float x2 = x * x;
  float t  = __builtin_fmaf(x2, -0.1029437f, -2.3022083f);
  float p  = __builtin_amdgcn_exp2f(x * t);
  return x * __builtin_amdgcn_rcpf(1.0f + p);
}

// ---------------- fused prep ----------------
__global__ void prep_kernel(const float* __restrict__ x, const float* __restrict__ W1,
                            const float* __restrict__ W2, short* __restrict__ xb,
                            short* __restrict__ w1f, short* __restrict__ w2f){
  int bid = blockIdx.x;
  if (bid < 2048){
    long i = (long)bid * 256 + threadIdx.x;   // 0..524287, 8 elems each
    const float4* p = (const float4*)(x + i * 8);
    float4 a = p[0], b = p[1];
    short8 v;
    v[0]=(short)f2bf(a.x); v[1]=(short)f2bf(a.y); v[2]=(short)f2bf(a.z); v[3]=(short)f2bf(a.w);
    v[4]=(short)f2bf(b.x); v[5]=(short)f2bf(b.y); v[6]=(short)f2bf(b.z); v[7]=(short)f2bf(b.w);
    *(short8*)(xb + i * 8) = v;
  } else if (threadIdx.x < 64){
    int f = bid - 2048, lane = threadIdx.x;
    short8 v;
    if (f < 48){
      int cb = f / 12, t = f % 12;
      #pragma unroll
      for (int j = 0; j < 8; j++)
        v[j] = (short)f2bf(W1[(t*16 + 8*(lane>>5) + j)*128 + cb*32 + (lane&31)]);
      *(short8*)(w1f + ((long)(f*64 + lane))*8) = v;
    } else {
      int g = f - 48; int w = g >> 2, q = g & 3;
      #pragma unroll
      for (int j = 0; j < 8; j++)
        v[j] = (short)f2bf(W2[(q*32 + 8*(lane>>4) + j)*64 + w*16 + (lane&15)]);
      *(short8*)(w2f + ((long)(g*64 + lane))*8) = v;
    }
  }
}

// ---------------- main kernel ----------------
// Per-tile LDS (9216 B), chunk-major:
//   own [slots 0..63]:   slot l written from row (l>>3)&3, chunk (l&7)^((l>>3)&3)  (2x dup)
//   j   [slots 64..319]: wave w instr -> slot (2w+hi)*32 + l31  (chunk-major [c][row])
//   k   [slots 320..575]
// GEMM1 j/k k-step reads = contiguous 1KB, conflict-free; own reads spread via XOR.
__global__ __launch_bounds__(256, 8) void ltc_main(
    const short* __restrict__ xb,  const short* __restrict__ w1f,
    const short* __restrict__ w2f, const int* __restrict__ jidx,
    const int* __restrict__ kidx,  const float* __restrict__ b1,
    const float* __restrict__ b2,  float* __restrict__ out)
{
  __shared__ short Ab[2][4608];     // 2 x 9 KB (576 slots x 8 shorts)
  __shared__ short HB[2][4 * 136];  // hbar ping-pong: 4 rows x 128 h, stride 136

  const int tid  = threadIdx.x;
  const int w    = tid >> 6, lane = tid & 63;   // w = cb = GEMM2 col-tile
  const int l31  = lane & 31, hi = lane >> 5;
  const int l15  = lane & 15, q4 = lane >> 4;

  // resident weight fragments
  short8 w1v[12];
  #pragma unroll
  for (int t = 0; t < 12; t++)
    w1v[t] = *(const short8*)(w1f + ((long)((w * 12 + t) * 64 + lane)) * 8);
  short8 w2v[4];
  #pragma unroll
  for (int q = 0; q < 4; q++)
    w2v[q] = *(const short8*)(w2f + ((long)((w * 4 + q) * 64 + lane)) * 8);

  float b1v = b1[w * 32 + l31];
  float b2v = b2[w * 16 + l15];

  const int bid   = blockIdx.x;
  const int batch = bid & 7;
  const int tile0 = batch * 2048 + (bid >> 3) * NT;   // 32-token tiles, batch-affine XCD swizzle
  const long tb0  = (long)tile0 * 32;
  const int bbase = batch << 13;                      // batch row base (b*8192)

  // own staging source (wave 0): lane l -> row (l>>3)&3, chunk (l&7)^((l>>3)&3)
  const int o_r = (lane >> 3) & 3;
  const int o_c = (lane & 7) ^ o_r;

  // GEMM1 read base byte offsets
  const int rown = l31 >> 3;                 // own row group (n-local)
  const int oOb  = rown * 128;
  const int oJ   = 1024 + hi * 512 + l31 * 16;
  const int oK   = oJ + 4096;

  auto stage = [&](int buf, long tb, int jn, int kn){
    const short* gj = xb + (long)(bbase + jn) * 64 + (2 * w + hi) * 8;
    __builtin_amdgcn_global_load_lds(
        (const __attribute__((address_space(1))) unsigned int*)gj,
        (__attribute__((address_space(3))) unsigned int*)(&Ab[buf][512 + w * 512]), 16, 0, 0);
    const short* gk = xb + (long)(bbase + kn) * 64 + (2 * w + hi) * 8;
    __builtin_amdgcn_global_load_lds(
        (const __attribute__((address_space(1))) unsigned int*)gk,
        (__attribute__((address_space(3))) unsigned int*)(&Ab[buf][2560 + w * 512]), 16, 0, 0);
    if (w == 0){
      const short* go = xb + (long)((int)(tb >> 3) + o_r) * 64 + o_c * 8;
      __builtin_amdgcn_global_load_lds(
          (const __attribute__((address_space(1))) unsigned int*)go,
          (__attribute__((address_space(3))) unsigned int*)(&Ab[buf][0]), 16, 0, 0);
    }
  };

  auto gemm2_store = [&](int buf, int ttp){
    f32x4 acc2 = {0.f, 0.f, 0.f, 0.f};
    #pragma unroll
    for (int q = 0; q < 4; q++){
      // A-frag: hbar[n = l15&3][k = 32q + 8*q4 + j]
      short8 hbf = *(const short8*)((const char*)&HB[buf][0] + (l15 & 3) * 272 + q * 64 + q4 * 16);
      acc2 = __builtin_amdgcn_mfma_f32_16x16x32_bf16(hbf, w2v[q], acc2, 0, 0, 0);
    }
    if (lane < 16){                       // C rows 0-3 = the 4 valid n
      long Gn = ((long)(tile0 + ttp)) * 4;
      #pragma unroll
      for (int r = 0; r < 4; r++)
        out[(Gn + r) * 64 + w * 16 + l15] = acc2[r] + b2v;
    }
  };

  // prologue
  int jn0 = jidx[tb0 + l31], kn0 = kidx[tb0 + l31];
  stage(0, tb0, jn0, kn0);
  int jnS = 0, knS = 0;
  if (NT > 1){ jnS = jidx[tb0 + 32 + l31]; knS = kidx[tb0 + 32 + l31]; }

  for (int tt = 0; tt < NT; ++tt){
    const int cur = tt & 1;
    asm volatile("s_waitcnt vmcnt(0) lgkmcnt(0)\n\ts_barrier" ::: "memory");  // Ab[cur]+HB[cur^1] ready
    if (tt + 1 < NT) stage(cur ^ 1, tb0 + (long)(tt + 1) * 32, jnS, knS);
    if (tt + 2 < NT){
      jnS = jidx[tb0 + (long)(tt + 2) * 32 + l31];
      knS = kidx[tb0 + (long)(tt + 2) * 32 + l31];
    }

    // deferred GEMM2 of previous tile (HB[cur^1] published before this tile's barrier)
    if (tt > 0) gemm2_store(cur ^ 1, tt - 1);

    // GEMM1: C[32 tok][32 h], C-init = b1
    const char* Abase = (const char*)&Ab[cur][0];
    f32x16 acc;
    #pragma unroll
    for (int r = 0; r < 16; r++) acc[r] = b1v;
    __builtin_amdgcn_s_setprio(1);
    #pragma unroll
    for (int t = 0; t < 12; t++){
      int off;
      if (t < 4)       off = oOb + (((2*t + hi) ^ rown) << 4);
      else if (t < 8)  off = oJ + (t - 4) * 1024;
      else             off = oK + (t - 8) * 1024;
      short8 af = *(const short8*)(Abase + off);
      acc = __builtin_amdgcn_mfma_f32_32x32x16_bf16(af, w1v[t], acc, 0, 0, 0);
    }
    __builtin_amdgcn_s_setprio(0);

    // GELU + s-reduce: token row=(reg&3)+8*(reg>>2)+4*hi -> n-group o=reg>>2, s=(reg&3)+4*hi
    #pragma unroll
    for (int o = 0; o < 4; o++){
      float s0 = fast_gelu(acc[4*o+0]);
      s0 += fast_gelu(acc[4*o+1]);
      s0 += fast_gelu(acc[4*o+2]);
      s0 += fast_gelu(acc[4*o+3]);
      float other = __shfl_xor(s0, 32);
      float hbv = (s0 + other) * 0.125f;
      if (hi == 0)
        HB[cur][o * 136 + w * 32 + l31] = (short)f2bf(hbv);
    }
  }

  // epilogue: last tile's GEMM2
  asm volatile("s_waitcnt lgkmcnt(0)\n\ts_barrier" ::: "memory");
  gemm2_store((NT - 1) & 1, NT - 1);
}

// ---------------- fallback (ws too small): correct, slow ----------------
__global__ void ltc_naive(const float* __restrict__ x, const int* __restrict__ jidx,
                          const int* __restrict__ kidx, const float* __restrict__ W1,
                          const float* __restrict__ b1, const float* __restrict__ W2,
                          const float* __restrict__ b2, float* __restrict__ out)
{
  int gidx = blockIdx.x;            // b*8192+n
  int b = gidx >> 13;
  __shared__ float trip[8][192];
  __shared__ float hb[128];
  int t = threadIdx.x;              // 128
  for (int i = t; i < 8 * 192; i += 128){
    int s = i / 192, c = i - s * 192;
    int v = c >> 6, cc = c & 63;
    int src;
    if (v == 0)      src = gidx & 8191;
    else if (v == 1) src = jidx[gidx * 8 + s];
    else             src = kidx[gidx * 8 + s];
    trip[s][c] = x[((long)(b << 13) + src) * 64 + cc];
  }
  __syncthreads();
  float z[8];
  #pragma unroll
  for (int s = 0; s < 8; s++) z[s] = b1[t];
  for (int k = 0; k < 192; k++){
    float wv = W1[k * 128 + t];
    #pragma unroll
    for (int s = 0; s < 8; s++) z[s] = fmaf(trip[s][k], wv, z[s]);
  }
  float acc = 0.f;
  #pragma unroll
  for (int s = 0; s < 8; s++) acc += fast_gelu(z[s]);
  hb[t] = acc * 0.125f;
  __syncthreads();
  if (t < 64){
    float o = b2[t];
    for (int h = 0; h < 128; h++) o = fmaf(hb[h], W2[h * 64 + t], o);
    out[(long)gidx * 64 + t] = o;
  }
}

extern "C" void kernel_launch(void* const* d_in, const int* in_sizes, int n_in,
                              void* d_out, int out_size, void* d_ws, size_t ws_size,
                              hipStream_t stream) {
  const float* x   = (const float*)d_in[0];
  const int*   jix = (const int*)  d_in[1];
  const int*   kix = (const int*)  d_in[2];
  const float* W1  = (const float*)d_in[3];
  const float* b1  = (const float*)d_in[4];
  const float* W2  = (const float*)d_in[5];
  const float* b2  = (const float*)d_in[6];
  float* out = (float*)d_out;

  const size_t xb_elems  = (size_t)8 * 8192 * 64;        // 4,194,304 bf16
  const size_t w1f_elems = 48 * 64 * 8;
  const size_t w2f_elems = 16 * 64 * 8;
  const size_t need = (xb_elems + w1f_elems + w2f_elems) * sizeof(short);

  if (ws_size >= need){
    short* xb  = (short*)d_ws;
    short* w1f = xb + xb_elems;
    short* w2f = w1f + w1f_elems;
    prep_kernel<<<2112, 256, 0, stream>>>(x, W1, W2, xb, w1f, w2f);
    ltc_main<<<NBLK, 256, 0, stream>>>(xb, w1f, w2f, jix, kix, b1, b2, out);
  } else {
    ltc_naive<<<8 * 8192, 128, 0, stream>>>(x, jix, kix, W1, b1, W2, b2, out);
  }
}